// Round 1
// baseline (2330.577 us; speedup 1.0000x reference)
//
#include <hip/hip_runtime.h>

// Problem constants
#define Bb   8
#define Hh   128
#define Ww   128
#define Cc   512
#define NHh  16
#define HDd  32
#define Kk   7
#define Ss   9
#define HW   (Hh*Ww)          // 16384
#define Mtot (Bb*HW)          // 131072
#define KK2  (Kk*Kk)          // 49

// ----------------------------------------------------------------------------
// GEMM: C[M,512] = A[M,512] @ Bw[512,512]^T + bias[512]
// classic SGEMM: 128x128 tile, BK=16, 256 threads, 8x8 per thread (2x2 of 4x4)
// ----------------------------------------------------------------------------
__global__ __launch_bounds__(256) void gemm_bt(const float* __restrict__ A,
                                               const float* __restrict__ Bw,
                                               const float* __restrict__ bias,
                                               float* __restrict__ C)
{
    __shared__ float As[16][132];   // pad 132 -> 2-way max on stores (free)
    __shared__ float Bs[16][132];

    const int tid = threadIdx.x;
    const int m0  = blockIdx.y << 7;
    const int n0  = blockIdx.x << 7;
    const int row = tid >> 2;            // 0..63
    const int k4  = (tid & 3) << 2;      // 0,4,8,12
    const int tmg = (tid >> 4) << 2;     // 0..60
    const int tng = (tid & 15) << 2;     // 0..60

    float acc[8][8];
#pragma unroll
    for (int r = 0; r < 8; ++r)
#pragma unroll
        for (int c = 0; c < 8; ++c) acc[r][c] = 0.f;

    const float* Ap0 = A  + (size_t)(m0 + row) * 512 + k4;
    const float* Ap1 = Ap0 + (size_t)64 * 512;
    const float* Bp0 = Bw + (size_t)(n0 + row) * 512 + k4;
    const float* Bp1 = Bp0 + (size_t)64 * 512;

    for (int kb = 0; kb < 512; kb += 16) {
        float4 av0 = *(const float4*)(Ap0 + kb);
        float4 av1 = *(const float4*)(Ap1 + kb);
        float4 bv0 = *(const float4*)(Bp0 + kb);
        float4 bv1 = *(const float4*)(Bp1 + kb);
        __syncthreads();   // previous iter's LDS reads done before overwrite
        As[k4+0][row]    = av0.x; As[k4+1][row]    = av0.y;
        As[k4+2][row]    = av0.z; As[k4+3][row]    = av0.w;
        As[k4+0][row+64] = av1.x; As[k4+1][row+64] = av1.y;
        As[k4+2][row+64] = av1.z; As[k4+3][row+64] = av1.w;
        Bs[k4+0][row]    = bv0.x; Bs[k4+1][row]    = bv0.y;
        Bs[k4+2][row]    = bv0.z; Bs[k4+3][row]    = bv0.w;
        Bs[k4+0][row+64] = bv1.x; Bs[k4+1][row+64] = bv1.y;
        Bs[k4+2][row+64] = bv1.z; Bs[k4+3][row+64] = bv1.w;
        __syncthreads();
#pragma unroll
        for (int kk = 0; kk < 16; ++kk) {
            float ar[8], br[8];
            *(float4*)&ar[0] = *(const float4*)&As[kk][tmg];
            *(float4*)&ar[4] = *(const float4*)&As[kk][tmg + 64];
            *(float4*)&br[0] = *(const float4*)&Bs[kk][tng];
            *(float4*)&br[4] = *(const float4*)&Bs[kk][tng + 64];
#pragma unroll
            for (int r = 0; r < 8; ++r)
#pragma unroll
                for (int c = 0; c < 8; ++c)
                    acc[r][c] += ar[r] * br[c];
        }
    }

    const float4 bs0 = *(const float4*)(bias + n0 + tng);
    const float4 bs1 = *(const float4*)(bias + n0 + tng + 64);
#pragma unroll
    for (int r = 0; r < 8; ++r) {
        const int m = m0 + tmg + (r & 3) + ((r >> 2) << 6);
        float4 o0 = make_float4(acc[r][0] + bs0.x, acc[r][1] + bs0.y,
                                acc[r][2] + bs0.z, acc[r][3] + bs0.w);
        float4 o1 = make_float4(acc[r][4] + bs1.x, acc[r][5] + bs1.y,
                                acc[r][6] + bs1.z, acc[r][7] + bs1.w);
        *(float4*)(C + (size_t)m * 512 + n0 + tng)      = o0;
        *(float4*)(C + (size_t)m * 512 + n0 + tng + 64) = o1;
    }
}

// ----------------------------------------------------------------------------
// wgt[pix][k] = sum_{s,t} sims_p[s]*sims_q[t]*[sinds_p[s]==sinds_q[t]]
// one thread per pixel
// ----------------------------------------------------------------------------
__global__ __launch_bounds__(256) void wgt_kernel(const float* __restrict__ sims,
                                                  const int* __restrict__ sinds,
                                                  float* __restrict__ wgt)
{
    const int pix = blockIdx.x * 256 + threadIdx.x;      // < 131072
    const int b  = pix >> 14;
    const int ij = pix & 16383;
    const int i  = ij >> 7;
    const int j  = ij & 127;

    float os[Ss]; int oi[Ss];
    const float* sp = sims + (size_t)pix * Ss;
    const int*   ip = sinds + (size_t)pix * Ss;
#pragma unroll
    for (int s = 0; s < Ss; ++s) { os[s] = sp[s]; oi[s] = ip[s]; }

    const int si = min(max(i - 3, 0), Hh - Kk);
    const int sj = min(max(j - 3, 0), Ww - Kk);
    float* wp = wgt + (size_t)pix * KK2;

    int kidx = 0;
    for (int ki = 0; ki < Kk; ++ki) {
        const int ni = si + ki;
        for (int kj = 0; kj < Kk; ++kj, ++kidx) {
            const int nj = sj + kj;
            const int npix = (b << 14) + (ni << 7) + nj;
            const float* nsp = sims + (size_t)npix * Ss;
            const int*   nip = sinds + (size_t)npix * Ss;
            float acc = 0.f;
#pragma unroll
            for (int t = 0; t < Ss; ++t) {
                const int   nid = nip[t];
                const float nsm = nsp[t];
                float m = 0.f;
#pragma unroll
                for (int s = 0; s < Ss; ++s) m += (oi[s] == nid) ? os[s] : 0.f;
                acc += m * nsm;
            }
            wp[kidx] = acc;
        }
    }
}

// ----------------------------------------------------------------------------
// aggregation: out[pix][c] = sum_k attn[b,nh,i,j,k]*wgt[pix,k]*v[b,ni,nj,c]
// one block (128 threads) per pixel; thread -> 4 channels (float4), nh=tid/8
// ----------------------------------------------------------------------------
__global__ __launch_bounds__(128) void agg_kernel(const float* __restrict__ v,
                                                  const float* __restrict__ attn,
                                                  const float* __restrict__ wgt,
                                                  float* __restrict__ out)
{
    const int pix = blockIdx.x;
    const int b  = pix >> 14;
    const int ij = pix & 16383;
    const int i  = ij >> 7;
    const int j  = ij & 127;
    const int tid = threadIdx.x;
    const int nh  = tid >> 3;

    __shared__ float coef[NHh * KK2];   // 784
    const float* wp = wgt + (size_t)pix * KK2;
    for (int e = tid; e < NHh * KK2; e += 128) {
        const int h = e / KK2;
        const int k = e - h * KK2;
        coef[e] = attn[(((size_t)b * NHh + h) * HW + ij) * KK2 + k] * wp[k];
    }
    __syncthreads();

    const int si = min(max(i - 3, 0), Hh - Kk);
    const int sj = min(max(j - 3, 0), Ww - Kk);
    const float* vb = v + ((size_t)b << 23);     // b * 16384 * 512
    const float* cp = &coef[nh * KK2];

    float4 acc = make_float4(0.f, 0.f, 0.f, 0.f);
#pragma unroll
    for (int k = 0; k < KK2; ++k) {
        const int ni = si + k / Kk;
        const int nj = sj + k % Kk;
        const float4 vv = *(const float4*)(vb + ((size_t)((ni << 7) + nj) << 9) + (tid << 2));
        const float cf = cp[k];
        acc.x += cf * vv.x; acc.y += cf * vv.y;
        acc.z += cf * vv.z; acc.w += cf * vv.w;
    }
    *(float4*)(out + (size_t)pix * 512 + (tid << 2)) = acc;
}

// ----------------------------------------------------------------------------
extern "C" void kernel_launch(void* const* d_in, const int* in_sizes, int n_in,
                              void* d_out, int out_size, void* d_ws, size_t ws_size,
                              hipStream_t stream)
{
    const float* x      = (const float*)d_in[0];
    const float* attn   = (const float*)d_in[1];
    const float* sims   = (const float*)d_in[2];
    const int*   sinds  = (const int*)d_in[3];
    const float* v_w    = (const float*)d_in[4];
    const float* v_b    = (const float*)d_in[5];
    const float* proj_w = (const float*)d_in[6];
    const float* proj_b = (const float*)d_in[7];
    float* out = (float*)d_out;

    float* v       = (float*)d_ws;                 // 67,108,864 f32
    float* out_agg = v + (size_t)Mtot * Cc;        // 67,108,864 f32
    float* wgt     = out_agg + (size_t)Mtot * Cc;  // 131,072 * 49 f32

    // 1) v = x @ v_w^T + v_b
    gemm_bt<<<dim3(Cc / 128, Mtot / 128), 256, 0, stream>>>(x, v_w, v_b, v);
    // 2) superpixel pair weights
    wgt_kernel<<<dim3(Mtot / 256), 256, 0, stream>>>(sims, sinds, wgt);
    // 3) neighborhood aggregation
    agg_kernel<<<dim3(Mtot), 128, 0, stream>>>(v, attn, wgt, out_agg);
    // 4) out = out_agg @ proj_w^T + proj_b
    gemm_bt<<<dim3(Cc / 128, Mtot / 128), 256, 0, stream>>>(out_agg, proj_w, proj_b, out);
}

// Round 2
// 1975.669 us; speedup vs baseline: 1.1796x; 1.1796x over previous
//
#include <hip/hip_runtime.h>

#define Hh   128
#define Ww   128
#define Cc   512
#define NHh  16
#define Kk   7
#define Ss   9
#define HW   (Hh*Ww)          // 16384
#define Mtot (8*HW)           // 131072
#define KK2  (Kk*Kk)          // 49

typedef __attribute__((ext_vector_type(8))) short bf16x8;
typedef __attribute__((ext_vector_type(4))) float f32x4;

__device__ __forceinline__ unsigned short bf16_rn(float f) {
    union { float f; unsigned u; } v; v.f = f;
    unsigned r = v.u + 0x7fffu + ((v.u >> 16) & 1u);
    return (unsigned short)(r >> 16);
}
__device__ __forceinline__ float bf16_f32(unsigned short h) {
    union { unsigned u; float f; } v; v.u = ((unsigned)h) << 16; return v.f;
}

// ----------------------------------------------------------------------------
// split f32 -> (hi, lo) bf16.  n8 = n/8
// ----------------------------------------------------------------------------
__global__ __launch_bounds__(256) void split_kernel(const float* __restrict__ src,
                                                    unsigned short* __restrict__ dh,
                                                    unsigned short* __restrict__ dl,
                                                    int n8)
{
    for (int i = blockIdx.x * 256 + threadIdx.x; i < n8; i += gridDim.x * 256) {
        const float4* sp = (const float4*)src + (size_t)i * 2;
        const float4 a = sp[0], b = sp[1];
        const float vv[8] = {a.x, a.y, a.z, a.w, b.x, b.y, b.z, b.w};
        unsigned short h[8], l[8];
#pragma unroll
        for (int j = 0; j < 8; ++j) {
            h[j] = bf16_rn(vv[j]);
            l[j] = bf16_rn(vv[j] - bf16_f32(h[j]));
        }
        ushort4* dhp = (ushort4*)dh + (size_t)i * 2;
        ushort4* dlp = (ushort4*)dl + (size_t)i * 2;
        dhp[0] = make_ushort4(h[0], h[1], h[2], h[3]);
        dhp[1] = make_ushort4(h[4], h[5], h[6], h[7]);
        dlp[0] = make_ushort4(l[0], l[1], l[2], l[3]);
        dlp[1] = make_ushort4(l[4], l[5], l[6], l[7]);
    }
}

// ----------------------------------------------------------------------------
// C[M,512] = (Ah+Al)[M,512] @ (Wh+Wl)[512,512]^T + bias  (3-term bf16 split)
// 128x128 tile, BK=32 bf16, 4 waves (wave w stages tensor w), dbuf LDS 64KB.
// LDS per tensor (8KB): K-major subtiles, addr(m,kc) = kc*2048 + m*16
//   => a wave's ds_read_b128 fragment fetch is ~2-way bank aliased (free).
// MFMA 16x16x32_bf16: A-frag lane l = A[row=l&15][k=8*(l>>4)+j] (contig 16B),
// C/D: col=lane&15, row=(lane>>4)*4+reg  [m89/m91 verified mapping]
// ----------------------------------------------------------------------------
__global__ __launch_bounds__(256, 2) void gemm_split(
        const unsigned short* __restrict__ Ah, const unsigned short* __restrict__ Al,
        const unsigned short* __restrict__ Wh, const unsigned short* __restrict__ Wl,
        const float* __restrict__ bias, float* __restrict__ C)
{
    __shared__ char lds[65536];
    const int tid  = threadIdx.x;
    const int lane = tid & 63;
    const int w    = tid >> 6;          // wave id == staged-tensor id
    const int wr   = w >> 1, wc = w & 1;

    // XCD-chunked swizzle: 4096 blocks, 8 XCDs, 512/XCD; the 4 n-blocks of an
    // m-panel stay on one XCD (A-panel L2 reuse).
    const int id = ((blockIdx.x & 7) << 9) + (blockIdx.x >> 3);
    const int m0 = (id >> 2) << 7;
    const int n0 = (id & 3) << 7;

    const unsigned short* tb = (w == 0) ? Ah : (w == 1) ? Al : (w == 2) ? Wh : Wl;
    const int row0 = (w < 2) ? m0 : n0;
    const char* gl = (const char*)tb + ((size_t)(row0 + lane)) * 1024;  // row stride 512*2B

    f32x4 acc[4][4];
#pragma unroll
    for (int a = 0; a < 4; ++a)
#pragma unroll
        for (int b = 0; b < 4; ++b) acc[a][b] = (f32x4)0.f;

    // prologue: stage K-tile 0 into buffer 0
#pragma unroll
    for (int q = 0; q < 8; ++q)
        __builtin_amdgcn_global_load_lds(
            (const __attribute__((address_space(1))) void*)(gl + (q & 1) * 65536 + (q >> 1) * 16),
            (__attribute__((address_space(3))) void*)(&lds[w * 8192] + q * 1024), 16, 0, 0);
    __syncthreads();

    const int laneoff = ((lane >> 4) << 11) + ((lane & 15) << 4);
    const int aoff = laneoff + wr * 1024;
    const int boff = laneoff + wc * 1024;

    for (int kt = 0; kt < 16; ++kt) {
        const int cur = kt & 1;
        if (kt < 15) {                      // prefetch next K-tile into other buffer
            const char* gn = gl + (kt + 1) * 64;
            char* dst = &lds[(cur ^ 1) * 32768 + w * 8192];
#pragma unroll
            for (int q = 0; q < 8; ++q)
                __builtin_amdgcn_global_load_lds(
                    (const __attribute__((address_space(1))) void*)(gn + (q & 1) * 65536 + (q >> 1) * 16),
                    (__attribute__((address_space(3))) void*)(dst + q * 1024), 16, 0, 0);
        }
        const char* LA = &lds[cur * 32768];
        bf16x8 ah[4], alo[4], bh[4], blo[4];
#pragma unroll
        for (int mf = 0; mf < 4; ++mf) {
            ah[mf]  = *(const bf16x8*)(LA + aoff + mf * 256);
            alo[mf] = *(const bf16x8*)(LA + 8192 + aoff + mf * 256);
        }
#pragma unroll
        for (int nf = 0; nf < 4; ++nf) {
            bh[nf]  = *(const bf16x8*)(LA + 16384 + boff + nf * 256);
            blo[nf] = *(const bf16x8*)(LA + 24576 + boff + nf * 256);
        }
#pragma unroll
        for (int mi = 0; mi < 4; ++mi)
#pragma unroll
            for (int ni = 0; ni < 4; ++ni) {
                acc[mi][ni] = __builtin_amdgcn_mfma_f32_16x16x32_bf16(ah[mi],  bh[ni],  acc[mi][ni], 0, 0, 0);
                acc[mi][ni] = __builtin_amdgcn_mfma_f32_16x16x32_bf16(ah[mi],  blo[ni], acc[mi][ni], 0, 0, 0);
                acc[mi][ni] = __builtin_amdgcn_mfma_f32_16x16x32_bf16(alo[mi], bh[ni],  acc[mi][ni], 0, 0, 0);
            }
        __syncthreads();
    }

    const int crow = (lane >> 4) << 2;
    const int ccol = lane & 15;
#pragma unroll
    for (int ni = 0; ni < 4; ++ni) {
        const int col = n0 + wc * 64 + ni * 16 + ccol;
        const float bv = bias[col];
#pragma unroll
        for (int mi = 0; mi < 4; ++mi) {
            float* cp = C + (size_t)(m0 + wr * 64 + mi * 16 + crow) * 512 + col;
            cp[0]    = acc[mi][ni][0] + bv;
            cp[512]  = acc[mi][ni][1] + bv;
            cp[1024] = acc[mi][ni][2] + bv;
            cp[1536] = acc[mi][ni][3] + bv;
        }
    }
}

// ----------------------------------------------------------------------------
// wgt[pix][k] (unchanged from round 1)
// ----------------------------------------------------------------------------
__global__ __launch_bounds__(256) void wgt_kernel(const float* __restrict__ sims,
                                                  const int* __restrict__ sinds,
                                                  float* __restrict__ wgt)
{
    const int pix = blockIdx.x * 256 + threadIdx.x;
    const int b  = pix >> 14;
    const int ij = pix & 16383;
    const int i  = ij >> 7;
    const int j  = ij & 127;

    float os[Ss]; int oi[Ss];
    const float* sp = sims + (size_t)pix * Ss;
    const int*   ip = sinds + (size_t)pix * Ss;
#pragma unroll
    for (int s = 0; s < Ss; ++s) { os[s] = sp[s]; oi[s] = ip[s]; }

    const int si = min(max(i - 3, 0), Hh - Kk);
    const int sj = min(max(j - 3, 0), Ww - Kk);
    float* wp = wgt + (size_t)pix * KK2;

    int kidx = 0;
    for (int ki = 0; ki < Kk; ++ki) {
        const int ni = si + ki;
        for (int kj = 0; kj < Kk; ++kj, ++kidx) {
            const int nj = sj + kj;
            const int npix = (b << 14) + (ni << 7) + nj;
            const float* nsp = sims + (size_t)npix * Ss;
            const int*   nip = sinds + (size_t)npix * Ss;
            float acc = 0.f;
#pragma unroll
            for (int t = 0; t < Ss; ++t) {
                const int   nid = nip[t];
                const float nsm = nsp[t];
                float m = 0.f;
#pragma unroll
                for (int s = 0; s < Ss; ++s) m += (oi[s] == nid) ? os[s] : 0.f;
                acc += m * nsm;
            }
            wp[kidx] = acc;
        }
    }
}

// ----------------------------------------------------------------------------
// aggregation; epilogue writes hi/lo bf16 (feeds split-GEMM 2 directly)
// ----------------------------------------------------------------------------
__global__ __launch_bounds__(128) void agg_kernel(const float* __restrict__ v,
                                                  const float* __restrict__ attn,
                                                  const float* __restrict__ wgt,
                                                  unsigned short* __restrict__ oh,
                                                  unsigned short* __restrict__ ol)
{
    const int pix = blockIdx.x;
    const int b  = pix >> 14;
    const int ij = pix & 16383;
    const int i  = ij >> 7;
    const int j  = ij & 127;
    const int tid = threadIdx.x;
    const int nh  = tid >> 3;

    __shared__ float coef[NHh * KK2];
    const float* wp = wgt + (size_t)pix * KK2;
    for (int e = tid; e < NHh * KK2; e += 128) {
        const int h = e / KK2;
        const int k = e - h * KK2;
        coef[e] = attn[(((size_t)b * NHh + h) * HW + ij) * KK2 + k] * wp[k];
    }
    __syncthreads();

    const int si = min(max(i - 3, 0), Hh - Kk);
    const int sj = min(max(j - 3, 0), Ww - Kk);
    const float* vb = v + ((size_t)b << 23);
    const float* cp = &coef[nh * KK2];

    float4 acc = make_float4(0.f, 0.f, 0.f, 0.f);
#pragma unroll
    for (int k = 0; k < KK2; ++k) {
        const int ni = si + k / Kk;
        const int nj = sj + k % Kk;
        const float4 vv = *(const float4*)(vb + ((size_t)((ni << 7) + nj) << 9) + (tid << 2));
        const float cf = cp[k];
        acc.x += cf * vv.x; acc.y += cf * vv.y;
        acc.z += cf * vv.z; acc.w += cf * vv.w;
    }
    const size_t o = (size_t)pix * 512 + (tid << 2);
    const unsigned short h0 = bf16_rn(acc.x), h1 = bf16_rn(acc.y),
                         h2 = bf16_rn(acc.z), h3 = bf16_rn(acc.w);
    *(ushort4*)(oh + o) = make_ushort4(h0, h1, h2, h3);
    *(ushort4*)(ol + o) = make_ushort4(bf16_rn(acc.x - bf16_f32(h0)),
                                       bf16_rn(acc.y - bf16_f32(h1)),
                                       bf16_rn(acc.z - bf16_f32(h2)),
                                       bf16_rn(acc.w - bf16_f32(h3)));
}

// ----------------------------------------------------------------------------
extern "C" void kernel_launch(void* const* d_in, const int* in_sizes, int n_in,
                              void* d_out, int out_size, void* d_ws, size_t ws_size,
                              hipStream_t stream)
{
    const float* x      = (const float*)d_in[0];
    const float* attn   = (const float*)d_in[1];
    const float* sims   = (const float*)d_in[2];
    const int*   sinds  = (const int*)d_in[3];
    const float* v_w    = (const float*)d_in[4];
    const float* v_b    = (const float*)d_in[5];
    const float* proj_w = (const float*)d_in[6];
    const float* proj_b = (const float*)d_in[7];
    float* out = (float*)d_out;

    // workspace layout (564.7 MB total):
    //   v:   268,435,456 B f32
    //   xh/xl: 2 x 134,217,728 B bf16  (reused as aggh/aggl after gemm1)
    //   wgt: 25,690,112 B f32
    //   w splits: 4 x 524,288 B bf16
    char* ws = (char*)d_ws;
    float*          v   = (float*)ws;
    unsigned short* xh  = (unsigned short*)(ws + 268435456);
    unsigned short* xl  = (unsigned short*)(ws + 268435456 + 134217728);
    float*          wgt = (float*)(ws + 536870912);
    unsigned short* vwh = (unsigned short*)(ws + 536870912 + 25690112);
    unsigned short* vwl = vwh + 262144;
    unsigned short* pwh = vwl + 262144;
    unsigned short* pwl = pwh + 262144;
    unsigned short* aggh = xh;   // x dead after gemm1
    unsigned short* aggl = xl;

    split_kernel<<<2048, 256, 0, stream>>>(x, xh, xl, Mtot * 512 / 8);
    split_kernel<<<128, 256, 0, stream>>>(v_w, vwh, vwl, 262144 / 8);
    split_kernel<<<128, 256, 0, stream>>>(proj_w, pwh, pwl, 262144 / 8);

    gemm_split<<<4096, 256, 0, stream>>>(xh, xl, vwh, vwl, v_b, v);
    wgt_kernel<<<512, 256, 0, stream>>>(sims, sinds, wgt);
    agg_kernel<<<Mtot, 128, 0, stream>>>(v, attn, wgt, aggh, aggl);
    gemm_split<<<4096, 256, 0, stream>>>(aggh, aggl, pwh, pwl, proj_b, out);
}